// Round 2
// baseline (814.293 us; speedup 1.0000x reference)
//
#include <hip/hip_runtime.h>
#include <math.h>

#define NB 32
#define HID 2560
#define NHD 32
#define NKVH 8
#define HD 80
#define LL 4096
#define QKVC 3840          // NH*D + 2*NKV*D
#define KOFF 2560
#define VOFF 3200
#define SCALE_F 0.11180339887498949f
#define NSPLIT 4
#define CHUNK 1024         // keys per attn block
#define TILE 64
#define KSPL 16            // gemm K-split
#define KCH 160            // 2560 / 16

// ws layout (floats): qkv[122880] attnout[81920] po[327680] pm[4096] ps[4096] P[1966080]
// total ~9.6 MB
#define WS_QKV 0
#define WS_ATT 122880
#define WS_PO  204800
#define WS_PM  532480
#define WS_PS  536576
#define WS_P   540672

// ---------------------------------------------------------------------------
// GEMM partials: P[s][32][NC] = X[32, s*160 : (s+1)*160] @ W[chunk, NC]
// 256 thr: 64 f4-cols x 4 row-groups(8 rows). W LDS-staged; X per-lane global
// (chunk rows fit L1; all lanes same addr -> multicast).  No atomics.
// ---------------------------------------------------------------------------
template<int NC>
__global__ __launch_bounds__(256)
void gemm_part_kernel(const float* __restrict__ X, const float* __restrict__ W,
                      float* __restrict__ P)
{
  const int t = threadIdx.x;
  const int c = t & 63;
  const int rg = t >> 6;
  const int cbase = blockIdx.x * 256;
  const int kbase = blockIdx.y * KCH;

  __shared__ float4 wt[32 * 64];   // 32 KB

  float4 acc[8];
#pragma unroll
  for (int r = 0; r < 8; ++r) acc[r] = make_float4(0.f, 0.f, 0.f, 0.f);

  for (int kt = 0; kt < KCH; kt += 32) {
#pragma unroll
    for (int i = 0; i < 8; ++i) {
      int idx = t + i * 256;
      int kr = idx >> 6, cc = idx & 63;
      wt[idx] = *(const float4*)(W + (size_t)(kbase + kt + kr) * NC + cbase + cc * 4);
    }
    __syncthreads();
#pragma unroll
    for (int k = 0; k < 32; k += 4) {
      float4 wv0 = wt[(k + 0) * 64 + c];
      float4 wv1 = wt[(k + 1) * 64 + c];
      float4 wv2 = wt[(k + 2) * 64 + c];
      float4 wv3 = wt[(k + 3) * 64 + c];
#pragma unroll
      for (int r = 0; r < 8; ++r) {
        float4 x4 = *(const float4*)(X + (size_t)(rg * 8 + r) * HID + kbase + kt + k);
        acc[r].x += x4.x * wv0.x + x4.y * wv1.x + x4.z * wv2.x + x4.w * wv3.x;
        acc[r].y += x4.x * wv0.y + x4.y * wv1.y + x4.z * wv2.y + x4.w * wv3.y;
        acc[r].z += x4.x * wv0.z + x4.y * wv1.z + x4.z * wv2.z + x4.w * wv3.z;
        acc[r].w += x4.x * wv0.w + x4.y * wv1.w + x4.z * wv2.w + x4.w * wv3.w;
      }
    }
    __syncthreads();
  }
#pragma unroll
  for (int r = 0; r < 8; ++r) {
    float* yp = P + (size_t)blockIdx.y * 32 * NC + (size_t)(rg * 8 + r) * NC + cbase + c * 4;
    *(float4*)yp = acc[r];
  }
}

// Y[i] = sum_s P[s*N + i]
__global__ __launch_bounds__(256)
void reduce_kernel(const float* __restrict__ P, float* __restrict__ Y, int N)
{
  int i4 = blockIdx.x * 256 + threadIdx.x;      // float4 index
  const float4* p4 = (const float4*)P;
  float4 a = make_float4(0.f, 0.f, 0.f, 0.f);
#pragma unroll
  for (int s = 0; s < KSPL; ++s) {
    float4 v = p4[(size_t)s * (N / 4) + i4];
    a.x += v.x; a.y += v.y; a.z += v.z; a.w += v.w;
  }
  ((float4*)Y)[i4] = a;
}

// ---------------------------------------------------------------------------
__global__ void rope_kernel(const int* __restrict__ pos, float* __restrict__ qkv)
{
  const int b = blockIdx.x;
  const float pf = (float)pos[b];
  for (int idx = threadIdx.x; idx < 400; idx += 256) {
    int h = idx / 10, j = idx % 10;
    int off = (h < NHD) ? (b * QKVC + h * HD)
                        : (b * QKVC + KOFF + (h - NHD) * HD);
    float e = (float)(2 * j) / 20.0f;
    float invf = 1.0f / powf(10000.0f, e);
    float ang = pf * invf;
    float sn, cs;
    sincosf(ang, &sn, &cs);
    float x1 = qkv[off + j], x2 = qkv[off + j + 10];
    qkv[off + j]      = x1 * cs - x2 * sn;
    qkv[off + j + 10] = x2 * cs + x1 * sn;
  }
}

// ---------------------------------------------------------------------------
// Attention partial: grid (256 bkv, 4 split), 320 threads (5 waves).
// Tile 64 keys, K LDS-staged (pad 21 f4) + reg prefetch, V direct global.
// 2 barriers/tile (double-buffered p/alpha). One QK wave per head.
// Split 3 also folds in the new token. Emits unnormalized o + (m, s).
// ---------------------------------------------------------------------------
__global__ __launch_bounds__(320)
void attn_kernel(const float* __restrict__ kc, const float* __restrict__ vc,
                 const float* __restrict__ qkv, float* __restrict__ po,
                 float* __restrict__ pm, float* __restrict__ ps)
{
  const int t = threadIdx.x;
  const int bkv = blockIdx.x;
  const int split = blockIdx.y;
  const int b = bkv >> 3;
  const int kv = bkv & 7;
  const int l0 = split * CHUNK;

  __shared__ float4 kbuf[TILE * 21];       // 21504 B
  __shared__ float4 q4[80];
  __shared__ float plds[2][4][68];
  __shared__ float mstate[4], sumstate[4], alpha_s[2][4], pnew[4];

  if (t < 4) { mstate[t] = -1e30f; sumstate[t] = 0.0f; }
  if (t < 80) {
    const float* qp = qkv + (size_t)b * QKVC + (kv * 4 + t / 20) * HD;
    q4[t] = *(const float4*)(qp + (t % 20) * 4);
  }

  const float* kb = kc + (size_t)bkv * (LL * HD);
  const float* vb = vc + (size_t)bkv * (LL * HD);

  const int srow = t / 20;                 // 0..15
  const int sd4  = t % 20;

  float4 kpre[4];
#pragma unroll
  for (int i = 0; i < 4; ++i)
    kpre[i] = *(const float4*)(kb + (size_t)(l0 + srow + 16 * i) * HD + sd4 * 4);

  const int qg = t >> 6;                   // QK: wave id = head (t<256)
  const int ql = t & 63;
  const int psub = t / 80;                 // PV: 16-key slice
  const int pg   = (t % 80) / 20;
  const int pd4  = t % 20;

  float4 acc = make_float4(0.f, 0.f, 0.f, 0.f);

  for (int tile = 0; tile < CHUNK / TILE; ++tile) {
#pragma unroll
    for (int i = 0; i < 4; ++i)
      kbuf[(srow + 16 * i) * 21 + sd4] = kpre[i];
    __syncthreads();                       // A
    if (tile < CHUNK / TILE - 1) {
#pragma unroll
      for (int i = 0; i < 4; ++i)
        kpre[i] = *(const float4*)(kb + (size_t)(l0 + (tile + 1) * TILE + srow + 16 * i) * HD + sd4 * 4);
    }
    if (t < 256) {
      float ss = 0.f;
#pragma unroll
      for (int d4 = 0; d4 < 20; ++d4) {
        float4 kk = kbuf[ql * 21 + d4];
        float4 qq = q4[qg * 20 + d4];
        ss += kk.x * qq.x + kk.y * qq.y + kk.z * qq.z + kk.w * qq.w;
      }
      float s = ss * SCALE_F;
      float wm = s;
#pragma unroll
      for (int off = 32; off >= 1; off >>= 1)
        wm = fmaxf(wm, __shfl_xor(wm, off, 64));
      float m_old = mstate[qg];
      float m_new = fmaxf(m_old, wm);
      float p = __expf(s - m_new);
      plds[tile & 1][qg][ql] = p;
      float wsum = p;
#pragma unroll
      for (int off = 32; off >= 1; off >>= 1)
        wsum += __shfl_xor(wsum, off, 64);
      if (ql == 0) {
        float a = __expf(m_old - m_new);
        sumstate[qg] = sumstate[qg] * a + wsum;
        mstate[qg] = m_new;
        alpha_s[tile & 1][qg] = a;
      }
    }
    __syncthreads();                       // B
    {
      float a = alpha_s[tile & 1][pg];
      acc.x *= a; acc.y *= a; acc.z *= a; acc.w *= a;
      const float* vrow = vb + (size_t)(l0 + tile * TILE + psub * 16) * HD + pd4 * 4;
#pragma unroll
      for (int i = 0; i < 16; ++i) {
        float pv = plds[tile & 1][pg][psub * 16 + i];
        float4 vv = *(const float4*)(vrow + (size_t)i * HD);
        acc.x += pv * vv.x; acc.y += pv * vv.y;
        acc.z += pv * vv.z; acc.w += pv * vv.w;
      }
    }
    // no barrier: plds/alpha double-buffered; kbuf rewritten only after A
  }

  __syncthreads();
  if (split == NSPLIT - 1) {               // new token (l = 4096)
    if (t < 20)
      kbuf[t] = *(const float4*)(qkv + (size_t)b * QKVC + KOFF + kv * HD + t * 4);
    __syncthreads();
    if (t < 4) {
      float ss = 0.f;
#pragma unroll
      for (int d4 = 0; d4 < 20; ++d4) {
        float4 kk = kbuf[d4];
        float4 qq = q4[t * 20 + d4];
        ss += kk.x * qq.x + kk.y * qq.y + kk.z * qq.z + kk.w * qq.w;
      }
      ss *= SCALE_F;
      float m_old = mstate[t];
      float m_new = fmaxf(m_old, ss);
      float a = __expf(m_old - m_new);
      float pn = __expf(ss - m_new);
      sumstate[t] = sumstate[t] * a + pn;
      mstate[t] = m_new;
      alpha_s[0][t] = a;
      pnew[t] = pn;
    }
    __syncthreads();
    {
      float a = alpha_s[0][pg];
      acc.x *= a; acc.y *= a; acc.z *= a; acc.w *= a;
      if (psub == 0) {
        float pn = pnew[pg];
        float4 vv = *(const float4*)(qkv + (size_t)b * QKVC + VOFF + kv * HD + pd4 * 4);
        acc.x += pn * vv.x; acc.y += pn * vv.y;
        acc.z += pn * vv.z; acc.w += pn * vv.w;
      }
    }
    __syncthreads();
  }

  kbuf[t] = acc;                           // reuse kbuf for slice combine
  __syncthreads();
  if (t < 80) {
    float4 o = make_float4(0.f, 0.f, 0.f, 0.f);
#pragma unroll
    for (int s = 0; s < 4; ++s) {
      float4 cp = kbuf[s * 80 + t];
      o.x += cp.x; o.y += cp.y; o.z += cp.z; o.w += cp.w;
    }
    ((float4*)po)[((size_t)bkv * 4 + split) * 80 + t] = o;
  }
  if (t < 4) {
    pm[bkv * 16 + split * 4 + t] = mstate[t];
    ps[bkv * 16 + split * 4 + t] = sumstate[t];
  }
}

// Combine split partials -> attnout. grid 256 (bkv), 320 threads.
__global__ __launch_bounds__(320)
void combine_kernel(const float* __restrict__ po, const float* __restrict__ pm,
                    const float* __restrict__ ps, float* __restrict__ attnout)
{
  const int t = threadIdx.x;
  const int bkv = blockIdx.x;
  const int g = t / 80, d = t % 80;
  float m0 = pm[bkv * 16 + 0 * 4 + g], m1 = pm[bkv * 16 + 1 * 4 + g];
  float m2 = pm[bkv * 16 + 2 * 4 + g], m3 = pm[bkv * 16 + 3 * 4 + g];
  float mf = fmaxf(fmaxf(m0, m1), fmaxf(m2, m3));
  float w0 = __expf(m0 - mf), w1 = __expf(m1 - mf);
  float w2 = __expf(m2 - mf), w3 = __expf(m3 - mf);
  float den = w0 * ps[bkv * 16 + 0 * 4 + g] + w1 * ps[bkv * 16 + 1 * 4 + g]
            + w2 * ps[bkv * 16 + 2 * 4 + g] + w3 * ps[bkv * 16 + 3 * 4 + g];
  const float* pob = po + (size_t)bkv * 1280 + g * 80 + d;
  float o = w0 * pob[0] + w1 * pob[320] + w2 * pob[640] + w3 * pob[960];
  const int b = bkv >> 3, kv = bkv & 7;
  attnout[(size_t)b * (NHD * HD) + (kv * 4 + g) * HD + d] = o / den;
}

// ---------------------------------------------------------------------------
extern "C" void kernel_launch(void* const* d_in, const int* in_sizes, int n_in,
                              void* d_out, int out_size, void* d_ws, size_t ws_size,
                              hipStream_t stream)
{
  const int*   positions = (const int*)d_in[0];
  const float* hidden    = (const float*)d_in[1];
  const float* k_cache   = (const float*)d_in[2];
  const float* v_cache   = (const float*)d_in[3];
  const float* w_qkv     = (const float*)d_in[4];
  const float* w_o       = (const float*)d_in[5];
  float* out = (float*)d_out;

  float* ws      = (float*)d_ws;
  float* qkv     = ws + WS_QKV;
  float* attnout = ws + WS_ATT;
  float* po      = ws + WS_PO;
  float* pm      = ws + WS_PM;
  float* ps      = ws + WS_PS;
  float* P       = ws + WS_P;

  gemm_part_kernel<QKVC><<<dim3(QKVC / 256, KSPL), 256, 0, stream>>>(hidden, w_qkv, P);
  reduce_kernel<<<NB * QKVC / 1024, 256, 0, stream>>>(P, qkv, NB * QKVC);
  rope_kernel<<<NB, 256, 0, stream>>>(positions, qkv);
  attn_kernel<<<dim3(NB * NKVH, NSPLIT), 320, 0, stream>>>(k_cache, v_cache, qkv, po, pm, ps);
  combine_kernel<<<NB * NKVH, 320, 0, stream>>>(po, pm, ps, attnout);
  gemm_part_kernel<HID><<<dim3(HID / 256, KSPL), 256, 0, stream>>>(attnout, w_o, P);
  reduce_kernel<<<NB * HID / 1024, 256, 0, stream>>>(P, out, NB * HID);
}